// Round 11
// baseline (83.209 us; speedup 1.0000x reference)
//
#include <hip/hip_runtime.h>
#include <hip/hip_bf16.h>

#define NROWS 8192
#define DIM 256
#define NSPLIT 16
#define JSPAN (NROWS / NSPLIT)   /* 512 cols per block */
#define NGRP (JSPAN / 16)        /* 32 16-col groups per wave */
#define RPW 64                   /* rows per wave (A stationary) */
#define RPB 256                  /* rows per block (4 waves) */
#define GRP_BYTES 8192           /* 16 cols x 512 B */

typedef __bf16 bf16x8 __attribute__((ext_vector_type(8)));
typedef float f32x4 __attribute__((ext_vector_type(4)));

#define NEG_LOG2E -1.4426950408889634f
#define NEG_LN2   -0.6931471805599453f

// ---- Kernel 1: L2-normalize rows of both inputs, fp32 -> bf16; zero accums ----
// En rows are additionally scaled by -log2(e) so the GEMM directly produces
// acc = -log2e * sim  ->  exp(-sim) = exp2(acc).
__global__ __launch_bounds__(256) void k_normalize_all(const float* __restrict__ emb,
                                                       const float* __restrict__ qry,
                                                       __hip_bfloat16* __restrict__ En,
                                                       __hip_bfloat16* __restrict__ Qn,
                                                       float* __restrict__ rowsum,
                                                       float* __restrict__ out) {
    if (blockIdx.x < 8)
        reinterpret_cast<float4*>(rowsum)[blockIdx.x * 256 + threadIdx.x] =
            float4{0.f, 0.f, 0.f, 0.f};
    if (blockIdx.x == 8 && threadIdx.x == 0) out[0] = 0.f;

    const int gr   = blockIdx.x * 4 + (threadIdx.x >> 6);
    const int lane = threadIdx.x & 63;
    const float* in;
    __hip_bfloat16* outp;
    int row;
    float scale;
    if (gr < NROWS) { in = emb; outp = En; row = gr;         scale = NEG_LOG2E; }
    else            { in = qry; outp = Qn; row = gr - NROWS; scale = 1.0f; }
    const float4 v = reinterpret_cast<const float4*>(in + (size_t)row * DIM)[lane];
    float ss = v.x * v.x + v.y * v.y + v.z * v.z + v.w * v.w;
#pragma unroll
    for (int m = 32; m >= 1; m >>= 1) ss += __shfl_xor(ss, m, 64);
    const float inv = scale / fmaxf(sqrtf(ss), 1e-8f);
    __hip_bfloat16 o[4];
    o[0] = __float2bfloat16(v.x * inv);
    o[1] = __float2bfloat16(v.y * inv);
    o[2] = __float2bfloat16(v.z * inv);
    o[3] = __float2bfloat16(v.w * inv);
    reinterpret_cast<ushort4*>(outp + (size_t)row * DIM)[lane] = *reinterpret_cast<const ushort4*>(o);
}

// Stage one 16-col group (8 KB) into a wave-private LDS buffer, K-MAJOR:
// chunk kk (1 KB) holds the 16 cols' 64B k-chunk kk. DMA lane l fetches
// col (l&15), k-subseg (l>>4): src = qlane + kk*64 (qlane = uniform base +
// fixed per-lane offset). HW writes dst + lane*16, which is EXACTLY the slot
// lane l reads back (vaddr = wbuf + lane*16, offset kk*1024): both sides
// contiguous 1 KB per access -> conflict-free, zero per-step addr VALU.
__device__ __forceinline__ void stage_group(const char* qlane, char* wdst) {
#pragma unroll
    for (int kk = 0; kk < 8; ++kk)
        __builtin_amdgcn_global_load_lds(
            (const __attribute__((address_space(1))) void*)(qlane + kk * 64),
            (__attribute__((address_space(3))) void*)(wdst + kk * 1024), 16, 0, 0);
}

// ---- Kernel 2: fused sim-GEMM + row sum of exp(-s) ----
// ZERO barriers. Each wave: 64 stationary A-rows (a[4][8]), private 2x8KB LDS
// double buffer. PREFETCH DEPTH 2 (the round-9 schedule that measured 44us,
// vs round-10's depth-1 at 74us): top-of-step counted vmcnt(8) waits for
// group p staged TWO steps earlier; stage(p+2) is issued after this step's
// ds_reads (guarded by lgkmcnt(0) - it overwrites the buffer just read).
__global__ __launch_bounds__(256, 2) void k_simlse(const __hip_bfloat16* __restrict__ En,
                                                   const __hip_bfloat16* __restrict__ Qn,
                                                   float* __restrict__ rowsum,
                                                   float* __restrict__ pickv) {
    __shared__ char lds[4][2][GRP_BYTES];   // [wave][buf] -> 64 KB/block
    const int bx   = blockIdx.x;
    const int ib   = bx >> 4;
    const int jq   = bx & 15;
    const int tid  = threadIdx.x;
    const int lane = tid & 63;
    const int w    = tid >> 6;
    const int l15  = lane & 15;
    const int lks  = lane >> 4;          // k-segment 0..3
    const int i0w  = ib * RPB + w * RPW;

    char* wbase = &lds[w][0][0];
    const char* rdbase = wbase + (size_t)lane * 16;   // this lane's read slot

    // A fragments: 64 rows x K=256 -> a[4][8] (128 regs).
    bf16x8 a[4][8];
    {
        const __hip_bfloat16* ab = En + (size_t)(i0w + l15) * DIM + lks * 8;
#pragma unroll
        for (int mi = 0; mi < 4; ++mi)
#pragma unroll
            for (int kk = 0; kk < 8; ++kk)
                a[mi][kk] = *reinterpret_cast<const bf16x8*>(ab + mi * 16 * DIM + kk * 32);
    }

    float racc[4][4];
#pragma unroll
    for (int mi = 0; mi < 4; ++mi)
#pragma unroll
        for (int r = 0; r < 4; ++r) racc[mi][r] = 0.0f;

    const int jq0 = jq * JSPAN;
    // Per-lane DMA source: col (lane&15), k-subseg (lane>>4); +8 KB per group.
    const char* qlane = (const char*)Qn + (size_t)jq0 * 512
                        + (size_t)l15 * 512 + (size_t)lks * 16;
    const char* qnext = qlane + 2 * GRP_BYTES;   // source for group p+2

    // One pipeline step; rdoff/stage parity compile-time via x2 unroll.
    auto step = [&](int p, int rdoff, const char* stsrc) {
        // Counted wait: group p's 8 DMAs were issued two steps ago; the 8
        // newest (group p+1, issued last step) stay in flight.
        if (p == NGRP - 1) asm volatile("s_waitcnt vmcnt(0)" ::: "memory");
        else               asm volatile("s_waitcnt vmcnt(8)" ::: "memory");

        // Contiguous conflict-free reads: same vaddr, 8 offset immediates.
        bf16x8 b[8];
#pragma unroll
        for (int kk = 0; kk < 8; ++kk)
            b[kk] = *reinterpret_cast<const bf16x8*>(rdbase + rdoff + kk * 1024);

        // b must be in registers before the DMA below overwrites this buffer
        // (same parity: p+2). Nearly free - MFMA waits on these loads anyway.
        asm volatile("s_waitcnt lgkmcnt(0)" ::: "memory");

        if (p + 2 < NGRP) stage_group(stsrc, wbase + rdoff);

        f32x4 acc[4];
#pragma unroll
        for (int mi = 0; mi < 4; ++mi) acc[mi] = f32x4{0.f, 0.f, 0.f, 0.f};

        __builtin_amdgcn_s_setprio(1);
#pragma unroll
        for (int kk = 0; kk < 8; ++kk)
#pragma unroll
            for (int mi = 0; mi < 4; ++mi)
                acc[mi] = __builtin_amdgcn_mfma_f32_16x16x32_bf16(
                    a[mi][kk], b[kk], acc[mi], 0, 0, 0);
        __builtin_amdgcn_s_setprio(0);

        // Epilogue (runs while next step's DMAs fly). acc = -log2e*s.
        // C/D layout: col = lane&15, row = (lane>>4)*4 + r.
        const int grpbase = jq0 + p * 16;
        const bool spec = (grpbase <= i0w + RPW) && (grpbase + 16 > i0w);
        if (!spec) {
#pragma unroll
            for (int mi = 0; mi < 4; ++mi)
#pragma unroll
                for (int r = 0; r < 4; ++r)
                    racc[mi][r] += __builtin_amdgcn_exp2f(acc[mi][r]);
        } else {
            const int jg = grpbase + l15;
#pragma unroll
            for (int mi = 0; mi < 4; ++mi) {
                const int ig0 = i0w + mi * 16 + lks * 4;
#pragma unroll
                for (int r = 0; r < 4; ++r) {
                    const float e  = __builtin_amdgcn_exp2f(acc[mi][r]);
                    const int   ig = ig0 + r;
                    racc[mi][r] += (jg == ig) ? 0.0f : e;
                    const int pc = (ig == NROWS - 1) ? (NROWS - 2) : (ig + 1);
                    if (jg == pc) pickv[ig] = acc[mi][r] * NEG_LN2;  // recover s
                }
            }
        }
    };

    // Prologue: stage groups 0 (buf0) and 1 (buf1).
    stage_group(qlane, wbase);
    stage_group(qlane + GRP_BYTES, wbase + GRP_BYTES);

    // Unrolled x2: buffer parity compile-time (even group -> buf0).
    for (int pp = 0; pp < NGRP; pp += 2) {
        step(pp,     0,         qnext);               // read buf0, stage p+2 -> buf0
        step(pp + 1, GRP_BYTES, qnext + GRP_BYTES);   // read buf1, stage p+3 -> buf1
        qnext += 2 * GRP_BYTES;
    }

    // Reduce row partials across the 16 col-lanes, one atomicAdd per row.
#pragma unroll
    for (int mi = 0; mi < 4; ++mi)
#pragma unroll
        for (int r = 0; r < 4; ++r) {
            float v = racc[mi][r];
            v += __shfl_xor(v, 1, 64);
            v += __shfl_xor(v, 2, 64);
            v += __shfl_xor(v, 4, 64);
            v += __shfl_xor(v, 8, 64);
            if (l15 == 0) atomicAdd(&rowsum[i0w + mi * 16 + lks * 4 + r], v);
        }
}

// ---- Kernel 3: final reduce, 16 blocks, one atomicAdd each (out pre-zeroed) ----
__global__ __launch_bounds__(256) void k_finalize(const float* __restrict__ rowsum,
                                                  const float* __restrict__ pickv,
                                                  float* __restrict__ out) {
    __shared__ float red[4];
    const int base = blockIdx.x * 512;
    float s = 0.0f;
#pragma unroll
    for (int it = 0; it < 2; ++it) {
        const int i = base + it * 256 + threadIdx.x;
        s += __logf(rowsum[i]) + pickv[i];
    }
#pragma unroll
    for (int m = 32; m >= 1; m >>= 1) s += __shfl_xor(s, m, 64);
    if ((threadIdx.x & 63) == 0) red[threadIdx.x >> 6] = s;
    __syncthreads();
    if (threadIdx.x == 0)
        atomicAdd(out, (red[0] + red[1] + red[2] + red[3]) * (1.0f / (float)NROWS));
}

extern "C" void kernel_launch(void* const* d_in, const int* in_sizes, int n_in,
                              void* d_out, int out_size, void* d_ws, size_t ws_size,
                              hipStream_t stream) {
    const float* emb = (const float*)d_in[0];
    const float* qry = (const float*)d_in[1];
    float* out = (float*)d_out;

    char* ws = (char*)d_ws;
    __hip_bfloat16* En = (__hip_bfloat16*)ws;                                  // 4 MB
    __hip_bfloat16* Qn = (__hip_bfloat16*)(ws + (size_t)NROWS * DIM * 2);      // 4 MB
    float* rowsum = (float*)(ws + (size_t)NROWS * DIM * 4);                    // 32 KB
    float* pickv  = rowsum + NROWS;                                            // 32 KB

    k_normalize_all<<<2 * NROWS / 4, 256, 0, stream>>>(emb, qry, En, Qn, rowsum, out);
    k_simlse<<<32 * NSPLIT, 256, 0, stream>>>(En, Qn, rowsum, pickv);
    k_finalize<<<16, 256, 0, stream>>>(rowsum, pickv, out);
}

// Round 12
// 53.553 us; speedup vs baseline: 1.5538x; 1.5538x over previous
//
#include <hip/hip_runtime.h>
#include <hip/hip_bf16.h>

#define NROWS 8192
#define DIM 256
#define NSPLIT 16
#define JSPAN (NROWS / NSPLIT)   /* 512 cols per block */
#define NGRP (JSPAN / 16)        /* 32 16-col groups per wave */
#define RPW 64                   /* rows per wave (A stationary) */
#define RPB 256                  /* rows per block (4 waves) */
#define GRP_BYTES 8192           /* 16 cols x 512 B, K-major-grouped */

typedef __bf16 bf16x8 __attribute__((ext_vector_type(8)));
typedef float f32x4 __attribute__((ext_vector_type(4)));

#define NEG_LOG2E -1.4426950408889634f
#define NEG_LN2   -0.6931471805599453f

// ---- Kernel 1: L2-normalize rows, fp32 -> bf16; zero accums ----
// En: row-major, scaled by -log2(e) (so GEMM acc = -log2e*sim; exp(-sim)=exp2(acc)).
// Qn: K-MAJOR-GROUPED layout. Group g = cols [16g,16g+16); chunk kk (1 KB) =
// the 16 cols' 64B K-slice kk, col-interleaved at 64B:
//   byte(col=16g+c, kbyte=kk*64+b) -> Qn + g*8192 + kk*1024 + c*64 + b.
// This makes BOTH the group DMA (lane*16 contiguous 1KB per chunk) and the
// MFMA-fragment ds_read (contiguous 1KB per k-step) perfectly coalesced.
__global__ __launch_bounds__(256) void k_normalize_all(const float* __restrict__ emb,
                                                       const float* __restrict__ qry,
                                                       __hip_bfloat16* __restrict__ En,
                                                       __hip_bfloat16* __restrict__ Qn,
                                                       float* __restrict__ rowsum,
                                                       float* __restrict__ out) {
    if (blockIdx.x < 8)
        reinterpret_cast<float4*>(rowsum)[blockIdx.x * 256 + threadIdx.x] =
            float4{0.f, 0.f, 0.f, 0.f};
    if (blockIdx.x == 8 && threadIdx.x == 0) out[0] = 0.f;

    const int gr   = blockIdx.x * 4 + (threadIdx.x >> 6);
    const int lane = threadIdx.x & 63;
    const bool isE = (gr < NROWS);
    const float* in = isE ? emb : qry;
    const int row   = isE ? gr : gr - NROWS;
    const float scale = isE ? NEG_LOG2E : 1.0f;

    const float4 v = reinterpret_cast<const float4*>(in + (size_t)row * DIM)[lane];
    float ss = v.x * v.x + v.y * v.y + v.z * v.z + v.w * v.w;
#pragma unroll
    for (int m = 32; m >= 1; m >>= 1) ss += __shfl_xor(ss, m, 64);
    const float inv = scale / fmaxf(sqrtf(ss), 1e-8f);
    __hip_bfloat16 o[4];
    o[0] = __float2bfloat16(v.x * inv);
    o[1] = __float2bfloat16(v.y * inv);
    o[2] = __float2bfloat16(v.z * inv);
    o[3] = __float2bfloat16(v.w * inv);
    const ushort4 o8 = *reinterpret_cast<const ushort4*>(o);

    if (isE) {
        reinterpret_cast<ushort4*>(En + (size_t)row * DIM)[lane] = o8;
    } else {
        // Lane's 8B = K-bytes [lane*8, lane*8+8) of this col's 512B row.
        const int g = row >> 4, c = row & 15;
        char* dst = (char*)Qn + (size_t)g * GRP_BYTES
                    + (size_t)(lane >> 3) * 1024 + c * 64 + (lane & 7) * 8;
        *reinterpret_cast<ushort4*>(dst) = o8;
    }
}

// Stage one 16-col group (8 KB, K-major-grouped) into a wave-private LDS
// buffer: 8 DMAs, each a CONTIGUOUS 1KB (lane l -> src + lane*16, LDS
// dst + lane*16 = identity copy). 8 full 128B lines per instruction.
__device__ __forceinline__ void stage_group(const char* qlane, char* wdst) {
#pragma unroll
    for (int kk = 0; kk < 8; ++kk)
        __builtin_amdgcn_global_load_lds(
            (const __attribute__((address_space(1))) void*)(qlane + kk * 1024),
            (__attribute__((address_space(3))) void*)(wdst + kk * 1024), 16, 0, 0);
}

// ---- Kernel 2: fused sim-GEMM + row sum of exp(-s) ----
// ZERO barriers. Each wave: 64 stationary A-rows (a[4][8]), private 2x8KB LDS
// double buffer, prefetch depth 2: top-of-step counted vmcnt(8) waits for
// group p (staged two steps earlier); stage(p+2) issued after this step's
// ds_reads (lgkmcnt(0) guard - it overwrites the buffer just read).
// Schedule identical to round 11; ONLY the DMA source pattern / LDS layout
// changed (both now contiguous-1KB per instruction).
__global__ __launch_bounds__(256, 2) void k_simlse(const __hip_bfloat16* __restrict__ En,
                                                   const __hip_bfloat16* __restrict__ Qn,
                                                   float* __restrict__ rowsum,
                                                   float* __restrict__ pickv) {
    __shared__ char lds[4][2][GRP_BYTES];   // [wave][buf] -> 64 KB/block
    const int bx   = blockIdx.x;
    const int ib   = bx >> 4;
    const int jq   = bx & 15;
    const int tid  = threadIdx.x;
    const int lane = tid & 63;
    const int w    = tid >> 6;
    const int l15  = lane & 15;
    const int lks  = lane >> 4;          // k-segment 0..3
    const int i0w  = ib * RPB + w * RPW;

    char* wbase = &lds[w][0][0];
    // Fragment read base: lane (l15,lks) owns bytes [l15*64+lks*16, +16) of
    // each 1KB chunk -> the 64 lanes tile the chunk exactly: conflict-free.
    const char* rdbase = wbase + l15 * 64 + lks * 16;

    // A fragments: 64 rows x K=256 -> a[4][8] (128 regs).
    bf16x8 a[4][8];
    {
        const __hip_bfloat16* ab = En + (size_t)(i0w + l15) * DIM + lks * 8;
#pragma unroll
        for (int mi = 0; mi < 4; ++mi)
#pragma unroll
            for (int kk = 0; kk < 8; ++kk)
                a[mi][kk] = *reinterpret_cast<const bf16x8*>(ab + mi * 16 * DIM + kk * 32);
    }

    float racc[4][4];
#pragma unroll
    for (int mi = 0; mi < 4; ++mi)
#pragma unroll
        for (int r = 0; r < 4; ++r) racc[mi][r] = 0.0f;

    const int jq0 = jq * JSPAN;
    // Per-lane DMA source: contiguous copy, advances 8 KB per group.
    const char* qlane = (const char*)Qn + (size_t)jq0 * 512 + (size_t)lane * 16;
    const char* qnext = qlane + 2 * GRP_BYTES;   // source for group p+2

    auto step = [&](int p, int rdoff, const char* stsrc) {
        // Counted wait: group p's 8 DMAs (issued two steps ago) done; the 8
        // newest (group p+1) stay in flight. Tail drains to 0.
        if (p == NGRP - 1) asm volatile("s_waitcnt vmcnt(0)" ::: "memory");
        else               asm volatile("s_waitcnt vmcnt(8)" ::: "memory");

        // 8 contiguous-1KB conflict-free reads: one vaddr, 8 offset imms.
        bf16x8 b[8];
#pragma unroll
        for (int kk = 0; kk < 8; ++kk)
            b[kk] = *reinterpret_cast<const bf16x8*>(rdbase + rdoff + kk * 1024);

        // b in registers before the DMA below overwrites this buffer (p+2,
        // same parity). Nearly free - the MFMAs wait on these loads anyway.
        asm volatile("s_waitcnt lgkmcnt(0)" ::: "memory");

        if (p + 2 < NGRP) stage_group(stsrc, wbase + rdoff);

        f32x4 acc[4];
#pragma unroll
        for (int mi = 0; mi < 4; ++mi) acc[mi] = f32x4{0.f, 0.f, 0.f, 0.f};

        __builtin_amdgcn_s_setprio(1);
#pragma unroll
        for (int kk = 0; kk < 8; ++kk)
#pragma unroll
            for (int mi = 0; mi < 4; ++mi)
                acc[mi] = __builtin_amdgcn_mfma_f32_16x16x32_bf16(
                    a[mi][kk], b[kk], acc[mi], 0, 0, 0);
        __builtin_amdgcn_s_setprio(0);

        // Epilogue (runs under next step's DMAs). acc = -log2e*s.
        // C/D layout: col = lane&15, row = (lane>>4)*4 + r.
        const int grpbase = jq0 + p * 16;
        const bool spec = (grpbase <= i0w + RPW) && (grpbase + 16 > i0w);
        if (!spec) {
#pragma unroll
            for (int mi = 0; mi < 4; ++mi)
#pragma unroll
                for (int r = 0; r < 4; ++r)
                    racc[mi][r] += __builtin_amdgcn_exp2f(acc[mi][r]);
        } else {
            const int jg = grpbase + l15;
#pragma unroll
            for (int mi = 0; mi < 4; ++mi) {
                const int ig0 = i0w + mi * 16 + lks * 4;
#pragma unroll
                for (int r = 0; r < 4; ++r) {
                    const float e  = __builtin_amdgcn_exp2f(acc[mi][r]);
                    const int   ig = ig0 + r;
                    racc[mi][r] += (jg == ig) ? 0.0f : e;
                    const int pc = (ig == NROWS - 1) ? (NROWS - 2) : (ig + 1);
                    if (jg == pc) pickv[ig] = acc[mi][r] * NEG_LN2;  // recover s
                }
            }
        }
    };

    // Prologue: stage groups 0 (buf0) and 1 (buf1).
    stage_group(qlane, wbase);
    stage_group(qlane + GRP_BYTES, wbase + GRP_BYTES);

    // Unrolled x2: buffer parity compile-time (even group -> buf0).
    for (int pp = 0; pp < NGRP; pp += 2) {
        step(pp,     0,         qnext);               // read buf0, stage p+2 -> buf0
        step(pp + 1, GRP_BYTES, qnext + GRP_BYTES);   // read buf1, stage p+3 -> buf1
        qnext += 2 * GRP_BYTES;
    }

    // Reduce row partials across the 16 col-lanes, one atomicAdd per row.
#pragma unroll
    for (int mi = 0; mi < 4; ++mi)
#pragma unroll
        for (int r = 0; r < 4; ++r) {
            float v = racc[mi][r];
            v += __shfl_xor(v, 1, 64);
            v += __shfl_xor(v, 2, 64);
            v += __shfl_xor(v, 4, 64);
            v += __shfl_xor(v, 8, 64);
            if (l15 == 0) atomicAdd(&rowsum[i0w + mi * 16 + lks * 4 + r], v);
        }
}

// ---- Kernel 3: final reduce, 16 blocks, one atomicAdd each (out pre-zeroed) ----
__global__ __launch_bounds__(256) void k_finalize(const float* __restrict__ rowsum,
                                                  const float* __restrict__ pickv,
                                                  float* __restrict__ out) {
    __shared__ float red[4];
    const int base = blockIdx.x * 512;
    float s = 0.0f;
#pragma unroll
    for (int it = 0; it < 2; ++it) {
        const int i = base + it * 256 + threadIdx.x;
        s += __logf(rowsum[i]) + pickv[i];
    }
#pragma unroll
    for (int m = 32; m >= 1; m >>= 1) s += __shfl_xor(s, m, 64);
    if ((threadIdx.x & 63) == 0) red[threadIdx.x >> 6] = s;
    __syncthreads();
    if (threadIdx.x == 0)
        atomicAdd(out, (red[0] + red[1] + red[2] + red[3]) * (1.0f / (float)NROWS));
}

extern "C" void kernel_launch(void* const* d_in, const int* in_sizes, int n_in,
                              void* d_out, int out_size, void* d_ws, size_t ws_size,
                              hipStream_t stream) {
    const float* emb = (const float*)d_in[0];
    const float* qry = (const float*)d_in[1];
    float* out = (float*)d_out;

    char* ws = (char*)d_ws;
    __hip_bfloat16* En = (__hip_bfloat16*)ws;                                  // 4 MB
    __hip_bfloat16* Qn = (__hip_bfloat16*)(ws + (size_t)NROWS * DIM * 2);      // 4 MB (K-major-grouped)
    float* rowsum = (float*)(ws + (size_t)NROWS * DIM * 4);                    // 32 KB
    float* pickv  = rowsum + NROWS;                                            // 32 KB

    k_normalize_all<<<2 * NROWS / 4, 256, 0, stream>>>(emb, qry, En, Qn, rowsum, out);
    k_simlse<<<32 * NSPLIT, 256, 0, stream>>>(En, Qn, rowsum, pickv);
    k_finalize<<<16, 256, 0, stream>>>(rowsum, pickv, out);
}